// Round 5
// baseline (3933.797 us; speedup 1.0000x reference)
//
#include <hip/hip_runtime.h>

// Problem dims
constexpr int kB    = 64;
constexpr int kT    = 512;
constexpr int kDin  = 256;
constexpr int kH    = 1024;
constexpr int kH3   = 3072;
constexpr int kDout = 256;
constexpr int kHB   = kB * kH;   // elements per ring slot (128 KB)

typedef float  f32x4  __attribute__((ext_vector_type(4)));
typedef __bf16 bf16x8 __attribute__((ext_vector_type(8)));
typedef unsigned u32x4 __attribute__((ext_vector_type(4)));
typedef unsigned long long u64;

__device__ __forceinline__ float b2f(unsigned short u) {
  union { float f; unsigned u32; } c; c.u32 = ((unsigned)u) << 16; return c.f;
}
__device__ __forceinline__ unsigned short f2b(float f) {
  union { float f; unsigned u32; } c; c.f = f;
  unsigned r = c.u32 + 0x7fffu + ((c.u32 >> 16) & 1u);  // RNE
  return (unsigned short)(r >> 16);
}
__device__ __forceinline__ bf16x8 ld8(const unsigned short* p) {
  return *reinterpret_cast<const bf16x8*>(p);
}
__device__ __forceinline__ u64 ald(const u64* p) {
  return __hip_atomic_load(p, __ATOMIC_RELAXED, __HIP_MEMORY_SCOPE_AGENT);
}
__device__ __forceinline__ unsigned ald32(const unsigned* p) {
  return __hip_atomic_load(p, __ATOMIC_RELAXED, __HIP_MEMORY_SCOPE_AGENT);
}
__device__ __forceinline__ void ast32(unsigned* p, unsigned v) {
  __hip_atomic_store(p, v, __ATOMIC_RELAXED, __HIP_MEMORY_SCOPE_AGENT);
}
__device__ __forceinline__ float sigm_(float x) { return 1.f / (1.f + __expf(-x)); }
__device__ __forceinline__ float tanh_(float x) {
  return 1.f - 2.f / (__expf(2.f * x) + 1.f);
}

#define MFMA16(a, b, c) __builtin_amdgcn_mfma_f32_16x16x32_bf16((a), (b), (c), 0, 0, 0)

// Swizzled column (in shorts) for linear column C + quad*8, C = kh*512+kk*32.
__device__ __forceinline__ int swzcol(int C, int quad) {
  return (C & ~63) + ((quad ^ (((C >> 3) ^ (C >> 6)) & 7)) << 3);
}

// Stage one 128B segment (seg index s) of a ring row into a swizzled LDS row.
__device__ __forceinline__ void stage_seg(unsigned short* ldsrow,
                                          const unsigned short* src, int s,
                                          int rmode) {
  if (rmode) {
    u32x4 d[8];
#pragma unroll
    for (int i = 0; i < 8; ++i) d[i] = *(const u32x4*)(src + i * 8);
#pragma unroll
    for (int i = 0; i < 8; ++i)
      *(u32x4*)&ldsrow[s * 64 + ((i ^ s) & 7) * 8] = d[i];
  } else {
    u64 w[16];
#pragma unroll
    for (int i = 0; i < 16; ++i) w[i] = ald((const u64*)src + i);
#pragma unroll
    for (int i = 0; i < 16; ++i)
      *(u64*)&ldsrow[s * 64 + (((i >> 1) ^ s) & 7) * 8 + (i & 1) * 4] = w[i];
  }
}

// Wave-pair spin barrier in LDS (monotonic target values, never reset).
__device__ __forceinline__ void pair_bar(unsigned* pb, int me, int other,
                                         unsigned val, int lane) {
  if (lane == 0)
    __hip_atomic_store(&pb[me], val, __ATOMIC_RELEASE,
                       __HIP_MEMORY_SCOPE_WORKGROUP);
  while (__hip_atomic_load(&pb[other], __ATOMIC_ACQUIRE,
                           __HIP_MEMORY_SCOPE_WORKGROUP) < val) {}
}

// sync[]: [0..255] fl0[mtile][64]; [256..511] fl1[mtile][64]
// ---------------------------------------------------------------------------
__global__ void gru_prep(const float* __restrict__ x,
                         const float* __restrict__ Wi0, const float* __restrict__ Wh0,
                         const float* __restrict__ bi0, const float* __restrict__ bh0,
                         const float* __restrict__ Wi1, const float* __restrict__ Wh1,
                         const float* __restrict__ bi1, const float* __restrict__ bh1,
                         unsigned short* __restrict__ xb,
                         unsigned short* __restrict__ wi0b, unsigned short* __restrict__ wh0b,
                         unsigned short* __restrict__ wi1b, unsigned short* __restrict__ wh1b,
                         unsigned short* __restrict__ r0, unsigned short* __restrict__ r1,
                         float* __restrict__ bias, unsigned* __restrict__ sync) {
  const int stride = gridDim.x * blockDim.x;
  const int g = blockIdx.x * blockDim.x + threadIdx.x;
  for (int i = g; i < kH3 * kDin; i += stride) wi0b[i] = f2b(Wi0[i]);
  for (int i = g; i < kH3 * kH; i += stride) {
    wh0b[i] = f2b(Wh0[i]); wi1b[i] = f2b(Wi1[i]); wh1b[i] = f2b(Wh1[i]);
  }
  for (int i = g; i < kB * kT * kDin; i += stride) xb[i] = f2b(x[i]);
  for (int i = g; i < kHB; i += stride) { r0[i] = 0; r1[i] = 0; }  // slot 0 = h[-1]
  for (int i = g; i < kH; i += stride) {
    bias[0 * kH + i] = bi0[0 * kH + i] + bh0[0 * kH + i];
    bias[1 * kH + i] = bi0[1 * kH + i] + bh0[1 * kH + i];
    bias[2 * kH + i] = bi0[2 * kH + i];
    bias[3 * kH + i] = bh0[2 * kH + i];
    bias[4 * kH + i] = bi1[0 * kH + i] + bh1[0 * kH + i];
    bias[5 * kH + i] = bi1[1 * kH + i] + bh1[1 * kH + i];
    bias[6 * kH + i] = bi1[2 * kH + i];
    bias[7 * kH + i] = bh1[2 * kH + i];
  }
  for (int i = g; i < 1024; i += stride) sync[i] = 0;
}

// ---------------------------------------------------------------------------
// Persistent GRU, decoupled dual-pipeline revision.
// 256 blocks x 256 thr. Waves 0-1 = L0 pipeline (own local step t); waves
// 2-3 = L1 pipeline (own local step tau). NO __syncthreads in the loop:
// each pair syncs through an LDS spin barrier (monotonic counters), so the
// two pipelines run at their own pace. L1 hoists the Wi1*h0 half of its
// GEMM before its fl1 wait. WAR safety: each pair publishes its flag only
// at the END of an iteration (after all reads of old slots), which gates
// every ring-slot reuse in both rmodes; LDS buffers are private per pair
// (hl0A vs hl0B/hl1) with barrier-ordered reuse (audit in comments above
// each barrier).
// ---------------------------------------------------------------------------
__global__ void __launch_bounds__(256, 1) gru_main(
    const unsigned short* __restrict__ xb,
    const unsigned short* __restrict__ wi0, const unsigned short* __restrict__ wh0,
    const unsigned short* __restrict__ wi1, const unsigned short* __restrict__ wh1,
    const float* __restrict__ bias,
    unsigned short* __restrict__ r0, unsigned short* __restrict__ r1,
    unsigned* __restrict__ sync, const int rmode,
    const float* __restrict__ Wo, const float* __restrict__ bo,
    float* __restrict__ out) {
  __shared__ unsigned short hl0A[16][1032];  // L0 pair: h0[t-1] (swizzled)
  __shared__ unsigned short hl0B[16][1032];  // L1 pair: h0[tau-1] (swizzled)
  __shared__ unsigned short hl1v[16][1032];  // L1 pair: h1[tau-2] (swizzled)
  __shared__ float red[2][4][64][5];         // [pair][gate][lane][reg(+pad)]
  __shared__ bf16x8 wlds[2][16][64];         // [kh][kk][lane] = Wh1_n frags
  __shared__ unsigned pbar[4];               // pair-barrier arrival counters

  const int tid  = threadIdx.x;
  const int lane = tid & 63;
  const int wv   = tid >> 6;        // 0..3
  const int ln15 = lane & 15;
  const int quad = lane >> 4;

  const int xcd   = blockIdx.x & 7;
  const int rest  = blockIdx.x >> 3;
  const int jsub  = rest & 7;
  const int mtile = rest >> 3;           // 0..3
  const int pidx  = xcd * 8 + jsub;      // producer index 0..63

  const int layer = wv >> 1;             // waves 0,1 -> L0; 2,3 -> L1
  const int kh    = wv & 1;              // K-half
  const int jrow  = xcd * 128 + jsub * 16 + ln15;
  const int jcol  = jrow;

  const unsigned short *pw_r, *pw_z, *pw_n, *pv_r, *pv_z, *pv_n;
  if (layer == 0) {
    pw_r = wh0 + (size_t)(0 * kH + jrow) * kH + kh * 512 + quad * 8;
    pw_z = wh0 + (size_t)(1 * kH + jrow) * kH + kh * 512 + quad * 8;
    pw_n = wh0 + (size_t)(2 * kH + jrow) * kH + kh * 512 + quad * 8;
    pv_r = wi0 + (size_t)(0 * kH + jrow) * kDin + kh * 128 + quad * 8;
    pv_z = wi0 + (size_t)(1 * kH + jrow) * kDin + kh * 128 + quad * 8;
    pv_n = wi0 + (size_t)(2 * kH + jrow) * kDin + kh * 128 + quad * 8;
  } else {
    pw_r = wh1 + (size_t)(0 * kH + jrow) * kH + kh * 512 + quad * 8;
    pw_z = wh1 + (size_t)(1 * kH + jrow) * kH + kh * 512 + quad * 8;
    pw_n = wh1 + (size_t)(2 * kH + jrow) * kH + kh * 512 + quad * 8;
    pv_r = wi1 + (size_t)(0 * kH + jrow) * kH + kh * 512 + quad * 8;
    pv_z = wi1 + (size_t)(1 * kH + jrow) * kH + kh * 512 + quad * 8;
    pv_n = wi1 + (size_t)(2 * kH + jrow) * kH + kh * 512 + quad * 8;
  }

  const float* bb = bias + layer * 4 * kH;
  const float b_r = bb[jcol];
  const float b_z = bb[kH + jcol];
  const float b_i = bb[2 * kH + jcol];
  const float b_h = bb[3 * kH + jcol];

  // Persistent weights.
  // L0: W[0..15]=Wh0_r, W[16..31]=Wh0_z, W[32..47]=Wh0_n, W[48..59]=Wi0 r/z/n
  // L1: W[0..15]=Wi1_r, W[16..31]=Wi1_z, W[32..47]=Wi1_n, W[48..63]=Wh1_r,
  //     W2[0..15]=Wh1_z; Wh1_n -> wlds (each wave reads only its own lane).
  bf16x8 W[64], W2[16];
  if (layer == 0) {
#pragma unroll
    for (int kk = 0; kk < 16; ++kk) {
      W[kk]      = ld8(pw_r + kk * 32);
      W[16 + kk] = ld8(pw_z + kk * 32);
      W[32 + kk] = ld8(pw_n + kk * 32);
    }
#pragma unroll
    for (int kk = 0; kk < 4; ++kk) {
      W[48 + kk] = ld8(pv_r + kk * 32);
      W[52 + kk] = ld8(pv_z + kk * 32);
      W[56 + kk] = ld8(pv_n + kk * 32);
    }
  } else {
#pragma unroll
    for (int kk = 0; kk < 16; ++kk) {
      W[kk]      = ld8(pv_r + kk * 32);
      W[16 + kk] = ld8(pv_z + kk * 32);
      W[32 + kk] = ld8(pv_n + kk * 32);
      W[48 + kk] = ld8(pw_r + kk * 32);
      W2[kk]     = ld8(pw_z + kk * 32);
      wlds[kh][kk][lane] = ld8(pw_n + kk * 32);
    }
  }

  if (tid < 4) pbar[tid] = 0;
  __syncthreads();   // pbar zero visible; the ONLY pre-epilogue block barrier

  const f32x4 z4 = {0.f, 0.f, 0.f, 0.f};
  unsigned* fl0 = sync + mtile * 64;
  unsigned* fl1 = sync + 256 + mtile * 64;

  float hprev[4] = {0.f, 0.f, 0.f, 0.f};

  if (layer == 0) {
    // ================= L0 pipeline (waves 0-1), local step t ================
    const int p    = tid;        // 0..127
    const int srow = p >> 3;     // staged row 0..15
    const int sseg = p & 7;      // segment base (handles sseg and sseg+8)
    for (int t = 0; t < kT; ++t) {
      const int s0r = rmode ? t : (t & 1);
      const int s0w = rmode ? (t + 1) : ((t + 1) & 1);
      f32x4 a_r = z4, a_z = z4, a_i = z4, a_h = z4;

      // x part: independent of h, overlaps the poll
      {
        const unsigned short* xp = xb + (size_t)(mtile * 16 + ln15) * (kT * kDin) +
                                   t * kDin + kh * 128 + quad * 8;
        bf16x8 xa[4];
#pragma unroll
        for (int i = 0; i < 4; ++i) xa[i] = ld8(xp + i * 32);
#pragma unroll
        for (int kk = 0; kk < 4; ++kk) {
          a_r = MFMA16(xa[kk], W[48 + kk], a_r);
          a_z = MFMA16(xa[kk], W[52 + kk], a_z);
          a_i = MFMA16(xa[kk], W[56 + kk], a_i);
        }
      }

      // poll: fl0 >= t (rmode0 additionally fl1 >= t-1 for parity WAR)
      for (;;) {
        int a = (int)ald32(fl0 + lane);
        bool ok;
        if (rmode) ok = __all(a >= t);
        else { int b = (int)ald32(fl1 + lane); ok = __all(a >= t && b >= t - 1); }
        if (ok) break;
        __builtin_amdgcn_s_sleep(1);
      }

      // stage hl0A (32 KB by 128 threads)
      {
        const unsigned short* rb =
            r0 + (size_t)s0r * kHB + (size_t)(mtile * 16 + srow) * kH;
        stage_seg(hl0A[srow], rb + sseg * 64, sseg, rmode);
        stage_seg(hl0A[srow], rb + (sseg + 8) * 64, sseg + 8, rmode);
      }
      pair_bar(pbar, wv, wv ^ 1, 2u * t + 1, lane);   // S1: staged

      const int kb = kh * 512;
#pragma unroll
      for (int kk = 0; kk < 16; ++kk) {
        bf16x8 A = *(const bf16x8*)&hl0A[ln15][swzcol(kb + kk * 32, quad)];
        a_r = MFMA16(A, W[kk], a_r);
        a_z = MFMA16(A, W[16 + kk], a_z);
        a_h = MFMA16(A, W[32 + kk], a_h);
      }

      if (wv == 1) {
#pragma unroll
        for (int q = 0; q < 4; ++q) {
          red[0][0][lane][q] = a_r[q]; red[0][1][lane][q] = a_z[q];
          red[0][2][lane][q] = a_i[q]; red[0][3][lane][q] = a_h[q];
        }
      }
      pair_bar(pbar, wv, wv ^ 1, 2u * t + 2, lane);   // S2: red ready

      if (wv == 0) {
        float hv4[4];
#pragma unroll
        for (int q = 0; q < 4; ++q) {
          float s_r = a_r[q] + red[0][0][lane][q];
          float s_z = a_z[q] + red[0][1][lane][q];
          float s_i = a_i[q] + red[0][2][lane][q];
          float s_h = a_h[q] + red[0][3][lane][q];
          float rg = sigm_(s_r + b_r);
          float zg = sigm_(s_z + b_z);
          float ng = tanh_(s_i + b_i + rg * (s_h + b_h));
          hv4[q] = (1.f - zg) * ng + zg * hprev[q];
          hprev[q] = hv4[q];
        }
        unsigned short* dst = r0 + (size_t)s0w * kHB;
#pragma unroll
        for (int q = 0; q < 4; ++q) {
          float pv = __shfl_xor(hv4[q], 1);
          if (!(lane & 1)) {
            unsigned pk = (unsigned)f2b(hv4[q]) | ((unsigned)f2b(pv) << 16);
            ast32((unsigned*)(dst + (size_t)(mtile * 16 + quad * 4 + q) * kH +
                              (jcol & ~1)),
                  pk);
          }
        }
        asm volatile("s_waitcnt vmcnt(0)" ::: "memory");
        if (lane == 0) ast32(&fl0[pidx], (unsigned)(t + 1));
      }
    }
  } else {
    // ================= L1 pipeline (waves 2-3), local step t ================
    // At local step t (1..kT) computes cell t-1: needs h0[t-1] (fl0>=t) and
    // h1[t-2] (fl1>=t-1). Wi1*h0 runs BEFORE the fl1 wait.
    const int p    = tid - 128;
    const int srow = p >> 3;
    const int sseg = p & 7;
    for (int t = 1; t <= kT; ++t) {
      const int s0r = rmode ? t : (t & 1);
      const int s1r = rmode ? (t - 1) : ((t - 1) & 1);
      const int s1w = rmode ? t : (t & 1);

      for (;;) {
        int a = (int)ald32(fl0 + lane);
        if (__all(a >= t)) break;
        __builtin_amdgcn_s_sleep(1);
      }
      {
        const unsigned short* rb =
            r0 + (size_t)s0r * kHB + (size_t)(mtile * 16 + srow) * kH;
        stage_seg(hl0B[srow], rb + sseg * 64, sseg, rmode);
        stage_seg(hl0B[srow], rb + (sseg + 8) * 64, sseg + 8, rmode);
      }
      pair_bar(pbar, wv, wv ^ 1, 3u * (t - 1) + 1, lane);  // T1

      f32x4 a_r = z4, a_z = z4, a_i = z4, a_h = z4;
      const int kb = kh * 512;
#pragma unroll
      for (int kk = 0; kk < 16; ++kk) {
        bf16x8 A0 = *(const bf16x8*)&hl0B[ln15][swzcol(kb + kk * 32, quad)];
        a_r = MFMA16(A0, W[kk], a_r);
        a_z = MFMA16(A0, W[16 + kk], a_z);
        a_i = MFMA16(A0, W[32 + kk], a_i);
      }

      for (;;) {
        int b = (int)ald32(fl1 + lane);
        if (__all(b >= t - 1)) break;
        __builtin_amdgcn_s_sleep(1);
      }
      {
        const unsigned short* rb =
            r1 + (size_t)s1r * kHB + (size_t)(mtile * 16 + srow) * kH;
        stage_seg(hl1v[srow], rb + sseg * 64, sseg, rmode);
        stage_seg(hl1v[srow], rb + (sseg + 8) * 64, sseg + 8, rmode);
      }
      pair_bar(pbar, wv, wv ^ 1, 3u * (t - 1) + 2, lane);  // T2

#pragma unroll
      for (int kk = 0; kk < 16; ++kk) {
        bf16x8 A1 = *(const bf16x8*)&hl1v[ln15][swzcol(kb + kk * 32, quad)];
        a_r = MFMA16(A1, W[48 + kk], a_r);
        a_z = MFMA16(A1, W2[kk], a_z);
        a_h = MFMA16(A1, wlds[kh][kk][lane], a_h);
      }

      if (wv == 3) {
#pragma unroll
        for (int q = 0; q < 4; ++q) {
          red[1][0][lane][q] = a_r[q]; red[1][1][lane][q] = a_z[q];
          red[1][2][lane][q] = a_i[q]; red[1][3][lane][q] = a_h[q];
        }
      }
      pair_bar(pbar, wv, wv ^ 1, 3u * (t - 1) + 3, lane);  // T3

      if (wv == 2) {
        float hv4[4];
#pragma unroll
        for (int q = 0; q < 4; ++q) {
          float s_r = a_r[q] + red[1][0][lane][q];
          float s_z = a_z[q] + red[1][1][lane][q];
          float s_i = a_i[q] + red[1][2][lane][q];
          float s_h = a_h[q] + red[1][3][lane][q];
          float rg = sigm_(s_r + b_r);
          float zg = sigm_(s_z + b_z);
          float ng = tanh_(s_i + b_i + rg * (s_h + b_h));
          hv4[q] = (1.f - zg) * ng + zg * hprev[q];
          hprev[q] = hv4[q];
        }
        unsigned short* dst = r1 + (size_t)s1w * kHB;
#pragma unroll
        for (int q = 0; q < 4; ++q) {
          float pv = __shfl_xor(hv4[q], 1);
          if (!(lane & 1)) {
            unsigned pk = (unsigned)f2b(hv4[q]) | ((unsigned)f2b(pv) << 16);
            ast32((unsigned*)(dst + (size_t)(mtile * 16 + quad * 4 + q) * kH +
                              (jcol & ~1)),
                  pk);
          }
        }
        asm volatile("s_waitcnt vmcnt(0)" ::: "memory");
        if (lane == 0) ast32(&fl1[pidx], (unsigned)t);
      }
    }
  }

  // ---------------- output projection: out = h1[511] @ Wo^T + bo -----------
  for (;;) {
    int f = (int)ald32(fl1 + lane);
    if (__all(f >= (int)kT)) break;
    __builtin_amdgcn_s_sleep(1);
  }
  __syncthreads();
  {
    const int sfin = rmode ? kT : 0;   // slot holding h1[511]
    const int r = tid >> 4, s = tid & 15;
    const unsigned short* b1 =
        r1 + (size_t)sfin * kHB + (size_t)(mtile * 16 + r) * kH + s * 64;
    if (rmode) {
      u32x4 d[8];
#pragma unroll
      for (int i = 0; i < 8; ++i) d[i] = *(const u32x4*)(b1 + i * 8);
#pragma unroll
      for (int i = 0; i < 8; ++i) *(u32x4*)&hl0A[r][s * 64 + i * 8] = d[i];
    } else {
      u64 w[16];
#pragma unroll
      for (int i = 0; i < 16; ++i) w[i] = ald((const u64*)b1 + i);
#pragma unroll
      for (int i = 0; i < 16; ++i) *(u64*)&hl0A[r][s * 64 + i * 4] = w[i];
    }
  }
  __syncthreads();
  {
    const int c  = tid & 31;
    const int rr = tid >> 5;
    const int col = jsub * 32 + c;
    const float* wr = Wo + (size_t)col * kH;
    float acc0 = bo[col], acc1 = bo[col];
#pragma unroll 8
    for (int k = 0; k < kH; k += 4) {
      float4 w4 = *reinterpret_cast<const float4*>(wr + k);
      acc0 += b2f(hl0A[rr][k]) * w4.x + b2f(hl0A[rr][k + 1]) * w4.y +
              b2f(hl0A[rr][k + 2]) * w4.z + b2f(hl0A[rr][k + 3]) * w4.w;
      acc1 += b2f(hl0A[rr + 8][k]) * w4.x + b2f(hl0A[rr + 8][k + 1]) * w4.y +
              b2f(hl0A[rr + 8][k + 2]) * w4.z + b2f(hl0A[rr + 8][k + 3]) * w4.w;
    }
    out[(mtile * 16 + rr) * kDout + col] = acc0;
    out[(mtile * 16 + rr + 8) * kDout + col] = acc1;
  }
}

// ---------------------------------------------------------------------------
extern "C" void kernel_launch(void* const* d_in, const int* in_sizes, int n_in,
                              void* d_out, int out_size, void* d_ws, size_t ws_size,
                              hipStream_t stream) {
  const float* x   = (const float*)d_in[0];
  const float* Wi0 = (const float*)d_in[1];
  const float* Wh0 = (const float*)d_in[2];
  const float* bi0 = (const float*)d_in[3];
  const float* bh0 = (const float*)d_in[4];
  const float* Wi1 = (const float*)d_in[5];
  const float* Wh1 = (const float*)d_in[6];
  const float* bi1 = (const float*)d_in[7];
  const float* bh1 = (const float*)d_in[8];
  const float* Wo  = (const float*)d_in[9];
  const float* bo  = (const float*)d_in[10];

  char* ws = (char*)d_ws;
  size_t off = 0;
  auto take = [&](size_t bytes) {
    size_t r = off;
    off += (bytes + 255) & ~(size_t)255;
    return r;
  };
  unsigned short* xb   = (unsigned short*)(ws + take((size_t)kB * kT * kDin * 2));
  unsigned short* wi0b = (unsigned short*)(ws + take((size_t)kH3 * kDin * 2));
  unsigned short* wh0b = (unsigned short*)(ws + take((size_t)kH3 * kH * 2));
  unsigned short* wi1b = (unsigned short*)(ws + take((size_t)kH3 * kH * 2));
  unsigned short* wh1b = (unsigned short*)(ws + take((size_t)kH3 * kH * 2));
  float*          bias = (float*)(ws + take(8 * kH * sizeof(float)));
  unsigned*       sync = (unsigned*)(ws + take(1024 * sizeof(unsigned)));

  // Ring: 513 slots of 128 KB per layer if workspace allows, else parity-2.
  const size_t slot_b = (size_t)kHB * 2;
  int rmode = 1;
  size_t ring_slots = (size_t)kT + 1;
  if (off + 2 * (ring_slots * slot_b) + (1u << 20) > ws_size) {
    rmode = 0;
    ring_slots = 2;
  }
  unsigned short* r0 = (unsigned short*)(ws + take(ring_slots * slot_b));
  unsigned short* r1 = (unsigned short*)(ws + take(ring_slots * slot_b));

  gru_prep<<<2048, 256, 0, stream>>>(x, Wi0, Wh0, bi0, bh0, Wi1, Wh1, bi1, bh1,
                                     xb, wi0b, wh0b, wi1b, wh1b, r0, r1, bias,
                                     sync);
  gru_main<<<256, 256, 0, stream>>>(xb, wi0b, wh0b, wi1b, wh1b, bias, r0, r1,
                                    sync, rmode, Wo, bo, (float*)d_out);
}

// Round 7
// 3318.882 us; speedup vs baseline: 1.1853x; 1.1853x over previous
//
#include <hip/hip_runtime.h>

// Problem dims
constexpr int kB    = 64;
constexpr int kT    = 512;
constexpr int kDin  = 256;
constexpr int kH    = 1024;
constexpr int kH3   = 3072;
constexpr int kDout = 256;
constexpr int kHB   = kB * kH;   // elements per ring slot (128 KB)

typedef float  f32x4  __attribute__((ext_vector_type(4)));
typedef __bf16 bf16x8 __attribute__((ext_vector_type(8)));
typedef unsigned u32x4 __attribute__((ext_vector_type(4)));
typedef unsigned long long u64;

__device__ __forceinline__ float b2f(unsigned short u) {
  union { float f; unsigned u32; } c; c.u32 = ((unsigned)u) << 16; return c.f;
}
__device__ __forceinline__ unsigned short f2b(float f) {
  union { float f; unsigned u32; } c; c.f = f;
  unsigned r = c.u32 + 0x7fffu + ((c.u32 >> 16) & 1u);  // RNE
  return (unsigned short)(r >> 16);
}
__device__ __forceinline__ bf16x8 ld8(const unsigned short* p) {
  return *reinterpret_cast<const bf16x8*>(p);
}
__device__ __forceinline__ u64 ald(const u64* p) {
  return __hip_atomic_load(p, __ATOMIC_RELAXED, __HIP_MEMORY_SCOPE_AGENT);
}
__device__ __forceinline__ unsigned ald32(const unsigned* p) {
  return __hip_atomic_load(p, __ATOMIC_RELAXED, __HIP_MEMORY_SCOPE_AGENT);
}
__device__ __forceinline__ void ast32(unsigned* p, unsigned v) {
  __hip_atomic_store(p, v, __ATOMIC_RELAXED, __HIP_MEMORY_SCOPE_AGENT);
}
__device__ __forceinline__ float sigm_(float x) { return 1.f / (1.f + __expf(-x)); }
__device__ __forceinline__ float tanh_(float x) {
  return 1.f - 2.f / (__expf(2.f * x) + 1.f);
}

#define MFMA16(a, b, c) __builtin_amdgcn_mfma_f32_16x16x32_bf16((a), (b), (c), 0, 0, 0)

// Swizzled column (in shorts) for linear column C + quad*8, C = kh*512+kk*32.
__device__ __forceinline__ int swzcol(int C, int quad) {
  return (C & ~63) + ((quad ^ (((C >> 3) ^ (C >> 6)) & 7)) << 3);
}

// sync[]: 8 replicated regions of 512 u32 (one per XCD-heuristic group):
//   region r: [r*512 + mtile*64 + p]        = fl0[mtile][p]
//             [r*512 + 256 + mtile*64 + p]  = fl1[mtile][p]
// Producers write ALL 8 regions; each consumer polls ONE region -> per-line
// fan-in drops 64 -> 8 consumers. Correct for any block->XCD mapping.
// ---------------------------------------------------------------------------
__global__ void gru_prep(const float* __restrict__ x,
                         const float* __restrict__ Wi0, const float* __restrict__ Wh0,
                         const float* __restrict__ bi0, const float* __restrict__ bh0,
                         const float* __restrict__ Wi1, const float* __restrict__ Wh1,
                         const float* __restrict__ bi1, const float* __restrict__ bh1,
                         unsigned short* __restrict__ xb,
                         unsigned short* __restrict__ wi0b, unsigned short* __restrict__ wh0b,
                         unsigned short* __restrict__ wi1b, unsigned short* __restrict__ wh1b,
                         unsigned short* __restrict__ r0, unsigned short* __restrict__ r1,
                         float* __restrict__ bias, unsigned* __restrict__ sync) {
  const int stride = gridDim.x * blockDim.x;
  const int g = blockIdx.x * blockDim.x + threadIdx.x;
  for (int i = g; i < kH3 * kDin; i += stride) wi0b[i] = f2b(Wi0[i]);
  for (int i = g; i < kH3 * kH; i += stride) {
    wh0b[i] = f2b(Wh0[i]); wi1b[i] = f2b(Wi1[i]); wh1b[i] = f2b(Wh1[i]);
  }
  for (int i = g; i < kB * kT * kDin; i += stride) xb[i] = f2b(x[i]);
  for (int i = g; i < kHB; i += stride) { r0[i] = 0; r1[i] = 0; }  // slot 0 = h[-1]
  for (int i = g; i < kH; i += stride) {
    bias[0 * kH + i] = bi0[0 * kH + i] + bh0[0 * kH + i];
    bias[1 * kH + i] = bi0[1 * kH + i] + bh0[1 * kH + i];
    bias[2 * kH + i] = bi0[2 * kH + i];
    bias[3 * kH + i] = bh0[2 * kH + i];
    bias[4 * kH + i] = bi1[0 * kH + i] + bh1[0 * kH + i];
    bias[5 * kH + i] = bi1[1 * kH + i] + bh1[1 * kH + i];
    bias[6 * kH + i] = bi1[2 * kH + i];
    bias[7 * kH + i] = bh1[2 * kH + i];
  }
  for (int i = g; i < 4096; i += stride) sync[i] = 0;
}

// ---------------------------------------------------------------------------
// Persistent GRU. 256 blocks x 256 thr (4 waves, 1 blk/CU, 1 wave/SIMD).
// Block = (xcd=blockIdx&7, jsub, mtile): 16 j-units x 16 batch rows; waves
// 0-1: L0@t (K-split-2), waves 2-3: L1@t-1. h exchange through a
// tick-indexed ring (rmode==1; rmode==0 = parity-2 fallback).
//
// THIS REVISION (R4 base + flag-line decongestion; s_sleep literal fix):
//  * Flags replicated into 8 sync regions; producers store to all 8, each
//    consumer polls only region blockIdx&7. Per-flag-line consumer fan-in
//    drops 64 -> 8 (R5's FETCH_SIZE evidence: polls are HBM ops and the
//    shared flag lines were queue-saturated at ~960 same-line ops/step).
//  * Two-phase poll pacing: first miss sleeps 16 (~0.43us), then 4.
//    (s_sleep arg must be a compile-time literal -> branch, not select.)
//  * Everything else identical to R4 (swizzled LDS staging, register
//    weights, hprev in regs, wave-local drained publish, 3 barriers).
// ---------------------------------------------------------------------------
__global__ void __launch_bounds__(256, 1) gru_main(
    const unsigned short* __restrict__ xb,
    const unsigned short* __restrict__ wi0, const unsigned short* __restrict__ wh0,
    const unsigned short* __restrict__ wi1, const unsigned short* __restrict__ wh1,
    const float* __restrict__ bias,
    unsigned short* __restrict__ r0, unsigned short* __restrict__ r1,
    unsigned* __restrict__ sync, const int rmode,
    const float* __restrict__ Wo, const float* __restrict__ bo,
    float* __restrict__ out) {
  __shared__ unsigned short hl0[16][1032];   // h0[t-1] rows of mtile (swizzled)
  __shared__ unsigned short hl1[16][1032];   // h1[t-2] rows of mtile (swizzled)
  __shared__ float red[2][4][64][5];         // [layer][gate][lane][reg(+pad)]
  __shared__ bf16x8 wlds[2][32][64];         // [kh][0..15 Wh1_z | 16..31 Wh1_n][lane]

  const int tid  = threadIdx.x;
  const int lane = tid & 63;
  const int wv   = tid >> 6;        // 0..3
  const int ln15 = lane & 15;
  const int quad = lane >> 4;

  const int xcd   = blockIdx.x & 7;      // L2-locality heuristic only
  const int rest  = blockIdx.x >> 3;
  const int jsub  = rest & 7;
  const int mtile = rest >> 3;           // 0..3
  const int pidx  = xcd * 8 + jsub;      // producer index 0..63

  const int layer = wv >> 1;             // waves 0,1 -> L0; 2,3 -> L1
  const int kh    = wv & 1;              // K-half
  const int jrow  = xcd * 128 + jsub * 16 + ln15;
  const int jcol  = jrow;

  const unsigned short *pw_r, *pw_z, *pw_n, *pv_r, *pv_z, *pv_n;
  if (layer == 0) {
    pw_r = wh0 + (size_t)(0 * kH + jrow) * kH + kh * 512 + quad * 8;
    pw_z = wh0 + (size_t)(1 * kH + jrow) * kH + kh * 512 + quad * 8;
    pw_n = wh0 + (size_t)(2 * kH + jrow) * kH + kh * 512 + quad * 8;
    pv_r = wi0 + (size_t)(0 * kH + jrow) * kDin + kh * 128 + quad * 8;
    pv_z = wi0 + (size_t)(1 * kH + jrow) * kDin + kh * 128 + quad * 8;
    pv_n = wi0 + (size_t)(2 * kH + jrow) * kDin + kh * 128 + quad * 8;
  } else {
    pw_r = wh1 + (size_t)(0 * kH + jrow) * kH + kh * 512 + quad * 8;
    pw_z = wh1 + (size_t)(1 * kH + jrow) * kH + kh * 512 + quad * 8;
    pw_n = wh1 + (size_t)(2 * kH + jrow) * kH + kh * 512 + quad * 8;
    pv_r = wi1 + (size_t)(0 * kH + jrow) * kH + kh * 512 + quad * 8;
    pv_z = wi1 + (size_t)(1 * kH + jrow) * kH + kh * 512 + quad * 8;
    pv_n = wi1 + (size_t)(2 * kH + jrow) * kH + kh * 512 + quad * 8;
  }

  // Bias scalars, loaded ONCE.
  const float* bb = bias + layer * 4 * kH;
  const float b_r = bb[jcol];
  const float b_z = bb[kH + jcol];
  const float b_i = bb[2 * kH + jcol];
  const float b_h = bb[3 * kH + jcol];

  // ---- persistent weight register file (256 VGPR, shared by both layers) --
  bf16x8 W[64];
  if (layer == 0) {
#pragma unroll
    for (int kk = 0; kk < 16; ++kk) {
      W[kk]      = ld8(pw_r + kk * 32);
      W[16 + kk] = ld8(pw_z + kk * 32);
      W[32 + kk] = ld8(pw_n + kk * 32);
    }
#pragma unroll
    for (int kk = 0; kk < 4; ++kk) {
      W[48 + kk] = ld8(pv_r + kk * 32);
      W[52 + kk] = ld8(pv_z + kk * 32);
      W[56 + kk] = ld8(pv_n + kk * 32);
    }
  } else {
#pragma unroll
    for (int kk = 0; kk < 16; ++kk) {
      W[kk]      = ld8(pv_r + kk * 32);
      W[16 + kk] = ld8(pv_z + kk * 32);
      W[32 + kk] = ld8(pv_n + kk * 32);
      W[48 + kk] = ld8(pw_r + kk * 32);
      wlds[kh][kk][lane]      = ld8(pw_z + kk * 32);
      wlds[kh][16 + kk][lane] = ld8(pw_n + kk * 32);
    }
  }

  const f32x4 z4 = {0.f, 0.f, 0.f, 0.f};
  // Region-local poll pointers; producers broadcast to all regions.
  unsigned* fl0 = sync + (size_t)xcd * 512 + mtile * 64;
  unsigned* fl1 = sync + (size_t)xcd * 512 + 256 + mtile * 64;

  float hprev[4] = {0.f, 0.f, 0.f, 0.f};   // this wave's own h tile at t-1

  for (int t = 0; t <= kT; ++t) {
    const bool l0c = (t < kT);
    const bool l1c = (t >= 1);
    // ring slots (rmode=1: tick index; rmode=0: parity)
    const int s0r = rmode ? t : (t & 1);
    const int s0w = rmode ? (t + 1) : ((t + 1) & 1);
    const int s1r = rmode ? (t >= 1 ? t - 1 : 0) : ((t >= 1 ? t - 1 : 0) & 1);
    const int s1w = rmode ? t : (t & 1);

    f32x4 a_r = z4, a_z = z4, a_i = z4, a_h = z4;

    // x fragment loads + x-part MFMAs (independent of h; overlap the poll)
    if (layer == 0 && l0c) {
      const unsigned short* xp = xb + (size_t)(mtile * 16 + ln15) * (kT * kDin) +
                                 t * kDin + kh * 128 + quad * 8;
      bf16x8 xa[4];
#pragma unroll
      for (int i = 0; i < 4; ++i) xa[i] = ld8(xp + i * 32);
#pragma unroll
      for (int kk = 0; kk < 4; ++kk) {
        a_r = MFMA16(xa[kk], W[48 + kk], a_r);
        a_z = MFMA16(xa[kk], W[52 + kk], a_z);
        a_i = MFMA16(xa[kk], W[56 + kk], a_i);
      }
    }

    // ---- wave 0 polls its region (paced); others park at B0 ---------------
    if (wv == 0) {
      int missed = 0;
      for (;;) {
        int a = (int)ald32(fl0 + lane);
        int b = (int)ald32(fl1 + lane);
        if (__all(a >= t && b >= t - 1)) break;
        if (!missed) { __builtin_amdgcn_s_sleep(16); missed = 1; }
        else         { __builtin_amdgcn_s_sleep(4); }
      }
    }
    __syncthreads();  // B0: h[t-1]/h[t-2] globally ready (+ parity WAR safe)

    // ---- stage h rows of mtile into LDS (XOR-swizzled chunk layout) -------
    {
      const int r = tid >> 4, s = tid & 15;   // row 0..15, 128B segment 0..15
      const unsigned short* b0 =
          r0 + (size_t)s0r * kHB + (size_t)(mtile * 16 + r) * kH + s * 64;
      const unsigned short* b1 =
          r1 + (size_t)s1r * kHB + (size_t)(mtile * 16 + r) * kH + s * 64;
      if (rmode) {
        u32x4 d0[8], d1[8];
#pragma unroll
        for (int i = 0; i < 8; ++i) d0[i] = *(const u32x4*)(b0 + i * 8);
#pragma unroll
        for (int i = 0; i < 8; ++i) d1[i] = *(const u32x4*)(b1 + i * 8);
#pragma unroll
        for (int i = 0; i < 8; ++i)
          *(u32x4*)&hl0[r][s * 64 + ((i ^ s) & 7) * 8] = d0[i];
#pragma unroll
        for (int i = 0; i < 8; ++i)
          *(u32x4*)&hl1[r][s * 64 + ((i ^ s) & 7) * 8] = d1[i];
      } else {
        u64 w0[16], w1[16];
#pragma unroll
        for (int i = 0; i < 16; ++i) w0[i] = ald((const u64*)b0 + i);
#pragma unroll
        for (int i = 0; i < 16; ++i) w1[i] = ald((const u64*)b1 + i);
#pragma unroll
        for (int i = 0; i < 16; ++i)
          *(u64*)&hl0[r][s * 64 + (((i >> 1) ^ s) & 7) * 8 + (i & 1) * 4] = w0[i];
#pragma unroll
        for (int i = 0; i < 16; ++i)
          *(u64*)&hl1[r][s * 64 + (((i >> 1) ^ s) & 7) * 8 + (i & 1) * 4] = w1[i];
      }
    }
    __syncthreads();  // B1: LDS staged

    // ---- MFMA (A from swizzled LDS; weights from registers / wlds) --------
    const bool active = (layer == 0) ? l0c : l1c;
    if (active) {
      const int kb = kh * 512;
      if (layer == 0) {
#pragma unroll
        for (int kk = 0; kk < 16; ++kk) {
          bf16x8 A = *(const bf16x8*)&hl0[ln15][swzcol(kb + kk * 32, quad)];
          a_r = MFMA16(A, W[kk], a_r);
          a_z = MFMA16(A, W[16 + kk], a_z);
          a_h = MFMA16(A, W[32 + kk], a_h);
        }
      } else {
#pragma unroll
        for (int kk = 0; kk < 16; ++kk) {
          bf16x8 A0 = *(const bf16x8*)&hl0[ln15][swzcol(kb + kk * 32, quad)];
          a_r = MFMA16(A0, W[kk], a_r);
          a_z = MFMA16(A0, W[16 + kk], a_z);
          a_i = MFMA16(A0, W[32 + kk], a_i);
          bf16x8 A1 = *(const bf16x8*)&hl1[ln15][swzcol(kb + kk * 32, quad)];
          a_r = MFMA16(A1, W[48 + kk], a_r);
          a_z = MFMA16(A1, wlds[kh][kk][lane], a_z);
          a_h = MFMA16(A1, wlds[kh][16 + kk][lane], a_h);
        }
      }
    }

    // ---- 2-way K-reduce ---------------------------------------------------
    if (((wv == 1) && l0c) || ((wv == 3) && l1c)) {
#pragma unroll
      for (int q = 0; q < 4; ++q) {
        red[layer][0][lane][q] = a_r[q]; red[layer][1][lane][q] = a_z[q];
        red[layer][2][lane][q] = a_i[q]; red[layer][3][lane][q] = a_h[q];
      }
    }
    __syncthreads();  // B2

    // ---- gates + h store + wave-local drained flag broadcast --------------
    if (((wv == 0) && l0c) || ((wv == 2) && l1c)) {
      float hv4[4];
#pragma unroll
      for (int q = 0; q < 4; ++q) {
        float sr = a_r[q] + red[layer][0][lane][q];
        float sz = a_z[q] + red[layer][1][lane][q];
        float si = a_i[q] + red[layer][2][lane][q];
        float sh = a_h[q] + red[layer][3][lane][q];
        float rg = sigm_(sr + b_r);
        float zg = sigm_(sz + b_z);
        float ng = tanh_(si + b_i + rg * (sh + b_h));
        hv4[q] = (1.f - zg) * ng + zg * hprev[q];
        hprev[q] = hv4[q];
      }
      unsigned short* dst = (layer == 0) ? r0 + (size_t)s0w * kHB
                                         : r1 + (size_t)s1w * kHB;
#pragma unroll
      for (int q = 0; q < 4; ++q) {
        float pv = __shfl_xor(hv4[q], 1);
        if (!(lane & 1)) {
          unsigned pk = (unsigned)f2b(hv4[q]) | ((unsigned)f2b(pv) << 16);
          unsigned* d = (unsigned*)(dst + (size_t)(mtile * 16 + quad * 4 + q) * kH +
                                    (jcol & ~1));
          ast32(d, pk);
        }
      }
      // Drain this wave's h stores, then broadcast flag to all 8 regions.
      asm volatile("s_waitcnt vmcnt(0)" ::: "memory");
      if (lane == 0) {
        const int base = (layer == 0) ? (mtile * 64 + pidx)
                                      : (256 + mtile * 64 + pidx);
        const unsigned val = (layer == 0) ? (unsigned)(t + 1) : (unsigned)t;
#pragma unroll
        for (int r8 = 0; r8 < 8; ++r8) ast32(sync + r8 * 512 + base, val);
      }
    }
    // no B3: red[] WAR is covered by B0+B1 of the next iteration.
  }

  // ---------------- output projection: out = h1[511] @ Wo^T + bo -----------
  if (wv == 0) {
    int missed = 0;
    for (;;) {
      int f = (int)ald32(fl1 + lane);
      if (__all(f >= (int)kT)) break;
      if (!missed) { __builtin_amdgcn_s_sleep(16); missed = 1; }
      else         { __builtin_amdgcn_s_sleep(4); }
    }
  }
  __syncthreads();
  // stage h1[511] rows of this mtile into LDS (UNswizzled; one-time)
  {
    const int sfin = rmode ? kT : 0;   // slot holding h1[511]
    const int r = tid >> 4, s = tid & 15;
    const unsigned short* b1 =
        r1 + (size_t)sfin * kHB + (size_t)(mtile * 16 + r) * kH + s * 64;
    if (rmode) {
      u32x4 d[8];
#pragma unroll
      for (int i = 0; i < 8; ++i) d[i] = *(const u32x4*)(b1 + i * 8);
#pragma unroll
      for (int i = 0; i < 8; ++i) *(u32x4*)&hl0[r][s * 64 + i * 8] = d[i];
    } else {
      u64 w[16];
#pragma unroll
      for (int i = 0; i < 16; ++i) w[i] = ald((const u64*)b1 + i);
#pragma unroll
      for (int i = 0; i < 16; ++i) *(u64*)&hl0[r][s * 64 + i * 4] = w[i];
    }
  }
  __syncthreads();
  {
    const int c  = tid & 31;          // 32 out cols per jsub
    const int rr = tid >> 5;          // rows rr and rr+8
    const int col = jsub * 32 + c;
    const float* wr = Wo + (size_t)col * kH;
    float acc0 = bo[col], acc1 = bo[col];
#pragma unroll 8
    for (int k = 0; k < kH; k += 4) {
      float4 w4 = *reinterpret_cast<const float4*>(wr + k);
      acc0 += b2f(hl0[rr][k]) * w4.x + b2f(hl0[rr][k + 1]) * w4.y +
              b2f(hl0[rr][k + 2]) * w4.z + b2f(hl0[rr][k + 3]) * w4.w;
      acc1 += b2f(hl0[rr + 8][k]) * w4.x + b2f(hl0[rr + 8][k + 1]) * w4.y +
              b2f(hl0[rr + 8][k + 2]) * w4.z + b2f(hl0[rr + 8][k + 3]) * w4.w;
    }
    out[(mtile * 16 + rr) * kDout + col] = acc0;
    out[(mtile * 16 + rr + 8) * kDout + col] = acc1;
  }
}

// ---------------------------------------------------------------------------
extern "C" void kernel_launch(void* const* d_in, const int* in_sizes, int n_in,
                              void* d_out, int out_size, void* d_ws, size_t ws_size,
                              hipStream_t stream) {
  const float* x   = (const float*)d_in[0];
  const float* Wi0 = (const float*)d_in[1];
  const float* Wh0 = (const float*)d_in[2];
  const float* bi0 = (const float*)d_in[3];
  const float* bh0 = (const float*)d_in[4];
  const float* Wi1 = (const float*)d_in[5];
  const float* Wh1 = (const float*)d_in[6];
  const float* bi1 = (const float*)d_in[7];
  const float* bh1 = (const float*)d_in[8];
  const float* Wo  = (const float*)d_in[9];
  const float* bo  = (const float*)d_in[10];

  char* ws = (char*)d_ws;
  size_t off = 0;
  auto take = [&](size_t bytes) {
    size_t r = off;
    off += (bytes + 255) & ~(size_t)255;
    return r;
  };
  unsigned short* xb   = (unsigned short*)(ws + take((size_t)kB * kT * kDin * 2));
  unsigned short* wi0b = (unsigned short*)(ws + take((size_t)kH3 * kDin * 2));
  unsigned short* wh0b = (unsigned short*)(ws + take((size_t)kH3 * kH * 2));
  unsigned short* wi1b = (unsigned short*)(ws + take((size_t)kH3 * kH * 2));
  unsigned short* wh1b = (unsigned short*)(ws + take((size_t)kH3 * kH * 2));
  float*          bias = (float*)(ws + take(8 * kH * sizeof(float)));
  unsigned*       sync = (unsigned*)(ws + take(4096 * sizeof(unsigned)));

  // Ring: 513 slots of 128 KB per layer if workspace allows, else parity-2.
  const size_t slot_b = (size_t)kHB * 2;
  int rmode = 1;
  size_t ring_slots = (size_t)kT + 1;
  if (off + 2 * (ring_slots * slot_b) + (1u << 20) > ws_size) {
    rmode = 0;
    ring_slots = 2;
  }
  unsigned short* r0 = (unsigned short*)(ws + take(ring_slots * slot_b));
  unsigned short* r1 = (unsigned short*)(ws + take(ring_slots * slot_b));

  gru_prep<<<2048, 256, 0, stream>>>(x, Wi0, Wh0, bi0, bh0, Wi1, Wh1, bi1, bh1,
                                     xb, wi0b, wh0b, wi1b, wh1b, r0, r1, bias,
                                     sync);
  gru_main<<<256, 256, 0, stream>>>(xb, wi0b, wh0b, wi1b, wh1b, bias, r0, r1,
                                    sync, rmode, Wo, bo, (float*)d_out);
}